// Round 2
// baseline (212.334 us; speedup 1.0000x reference)
//
#include <hip/hip_runtime.h>

// MultiHeadAttention: S=2048, B=2, EMB=512, H=8, D=64 -> 16 independent (b,h)
// groups of [2048 x 64] attention, plus per-head 64x64 QKV projections and a
// 512x512 output FC. All matmuls in bf16 MFMA (16x16x32), fp32 accumulate.
//
// R2: flash kernel computes S^T = K.Q^T so softmax state is per-lane scalar
// (2 shuffles/iter), K/V/Q fragments load straight from global (L2), no
// __syncthreads at all; P transform via per-wave LDS (4x ds_write_b64 +
// 2x ds_read_b128). Softmax scale folded into Q projection.
//
// ws layout (u16/bf16): Qb[32768*64] | Kb[32768*64] | Vt[16][64][2048] | Att[32768*64]

typedef __attribute__((ext_vector_type(8))) __bf16 bf16x8;
typedef __attribute__((ext_vector_type(4))) float f32x4;
typedef __attribute__((ext_vector_type(4))) unsigned short u16x4;
typedef __attribute__((ext_vector_type(4))) unsigned int u32x4;
typedef unsigned short u16;
typedef unsigned int u32;

static __device__ __forceinline__ u16 f2bf(float x) {
    u32 u = __float_as_uint(x);
    u += 0x7fff + ((u >> 16) & 1);   // RNE; inputs are normal floats (no NaN)
    return (u16)(u >> 16);
}
static __device__ __forceinline__ u32 pack2bf(float lo, float hi) {
    u32 a = __float_as_uint(lo), b = __float_as_uint(hi);
    a += 0x7fff + ((a >> 16) & 1);
    b += 0x7fff + ((b >> 16) & 1);
    return (a >> 16) | (b & 0xffff0000u);
}

// ---------------------------------------------------------------------------
// Kernel 1: QKV projection.  Y = (X @ W^T) * scale, X flat [32768 x 64].
// mode 0 -> Qb (scale = 1/sqrt(64) * log2(e)), mode 1 -> Kb, mode 2 -> Vt
// (transposed within group: Vt[(g*64+d)*2048 + s]).  Output staged through
// LDS for coalesced 16B global stores.
// ---------------------------------------------------------------------------
__global__ __launch_bounds__(256) void proj_kernel(
    const float* __restrict__ q, const float* __restrict__ k, const float* __restrict__ v,
    const float* __restrict__ Wq, const float* __restrict__ Wk, const float* __restrict__ Wv,
    u16* __restrict__ Qb, u16* __restrict__ Kb, u16* __restrict__ Vt)
{
    const int mode = blockIdx.z;
    const float* A = (mode == 0) ? q : (mode == 1) ? k : v;
    const float* W = (mode == 0) ? Wq : (mode == 1) ? Wk : Wv;
    const float osc = (mode == 0) ? 0.18033688011112042f : 1.0f; // 0.125*log2(e)

    __shared__ alignas(16) u16 Ash[128 * 88];   // also reused as output stage
    __shared__ alignas(16) u16 Wsh[64 * 88];

    const int t = threadIdx.x;
    const int m0 = blockIdx.x * 128;

    {   // stage A tile: 128 rows x 64 cols fp32 -> bf16 LDS
        const float4* A4 = (const float4*)(A + (size_t)m0 * 64);
        const int c4 = t & 15;
        #pragma unroll
        for (int i = 0; i < 8; ++i) {
            int row = (t >> 4) + i * 16;
            float4 val = A4[row * 16 + c4];
            u16x4 bb = { f2bf(val.x), f2bf(val.y), f2bf(val.z), f2bf(val.w) };
            *(u16x4*)(Ash + row * 88 + c4 * 4) = bb;
        }
        const float4* W4 = (const float4*)W;
        #pragma unroll
        for (int i = 0; i < 4; ++i) {
            int row = (t >> 4) + i * 16;
            float4 val = W4[row * 16 + c4];
            u16x4 bb = { f2bf(val.x), f2bf(val.y), f2bf(val.z), f2bf(val.w) };
            *(u16x4*)(Wsh + row * 88 + c4 * 4) = bb;
        }
    }
    __syncthreads();

    const int w = t >> 6, l = t & 63;
    const int r16 = l & 15, q4 = l >> 4;

    bf16x8 af[2][2], wf[4][2];
    #pragma unroll
    for (int mc = 0; mc < 2; ++mc)
        #pragma unroll
        for (int kk = 0; kk < 2; ++kk)
            af[mc][kk] = *(const bf16x8*)(Ash + (w * 32 + mc * 16 + r16) * 88 + kk * 32 + q4 * 8);
    #pragma unroll
    for (int nc = 0; nc < 4; ++nc)
        #pragma unroll
        for (int kk = 0; kk < 2; ++kk)
            wf[nc][kk] = *(const bf16x8*)(Wsh + (nc * 16 + r16) * 88 + kk * 32 + q4 * 8);

    f32x4 acc[2][4];
    const f32x4 zero = {0.f, 0.f, 0.f, 0.f};
    #pragma unroll
    for (int mc = 0; mc < 2; ++mc)
        #pragma unroll
        for (int nc = 0; nc < 4; ++nc) {
            acc[mc][nc] = zero;
            acc[mc][nc] = __builtin_amdgcn_mfma_f32_16x16x32_bf16(af[mc][0], wf[nc][0], acc[mc][nc], 0, 0, 0);
            acc[mc][nc] = __builtin_amdgcn_mfma_f32_16x16x32_bf16(af[mc][1], wf[nc][1], acc[mc][nc], 0, 0, 0);
        }

    __syncthreads();   // everyone done reading Ash/Wsh; reuse Ash as out-stage

    // C/D layout: col = lane&15, row = quad*4 + reg
    if (mode < 2) {
        u16* Ssh = Ash;                      // [128 rows][72]
        #pragma unroll
        for (int mc = 0; mc < 2; ++mc)
            #pragma unroll
            for (int nc = 0; nc < 4; ++nc)
                #pragma unroll
                for (int r = 0; r < 4; ++r)
                    Ssh[(w * 32 + mc * 16 + q4 * 4 + r) * 72 + nc * 16 + r16] = f2bf(acc[mc][nc][r] * osc);
        __syncthreads();
        u16* Out = ((mode == 0) ? Qb : Kb) + (size_t)m0 * 64;
        int row = t >> 1, cbase = (t & 1) * 32;
        #pragma unroll
        for (int i = 0; i < 4; ++i)
            *(u32x4*)(Out + row * 64 + cbase + i * 8) = *(const u32x4*)(Ssh + row * 72 + cbase + i * 8);
    } else {
        u16* Ssh = Ash;                      // [64 d][136 s]
        #pragma unroll
        for (int mc = 0; mc < 2; ++mc)
            #pragma unroll
            for (int nc = 0; nc < 4; ++nc)
                #pragma unroll
                for (int r = 0; r < 4; ++r)
                    Ssh[(nc * 16 + r16) * 136 + w * 32 + mc * 16 + q4 * 4 + r] = f2bf(acc[mc][nc][r]);
        __syncthreads();
        const int g = m0 >> 11, s0 = m0 & 2047;
        int d = t >> 2, sb = (t & 3) * 32;
        u16* Out = Vt + ((size_t)(g * 64 + d)) * 2048 + s0;
        #pragma unroll
        for (int i = 0; i < 4; ++i)
            *(u32x4*)(Out + sb + i * 8) = *(const u32x4*)(Ssh + d * 136 + sb + i * 8);
    }
}

// ---------------------------------------------------------------------------
// Kernel 2: flash attention, S^T orientation, barrier-free.
// Block = 4 waves; wave owns 16 q columns; K-tile = 64 keys, 32 iterations.
// Q pre-scaled by 1/sqrt(d)*log2e -> softmax in exp2 domain.
// ---------------------------------------------------------------------------
__global__ __launch_bounds__(256) void flash_kernel(
    const u16* __restrict__ Qb, const u16* __restrict__ Kb,
    const u16* __restrict__ Vt, u16* __restrict__ Att)
{
    const int g = blockIdx.y;    // 0..15
    const int qt = blockIdx.x;   // 0..31
    const int t = threadIdx.x, w = t >> 6, l = t & 63;
    const int r16 = l & 15, q4 = l >> 4;

    __shared__ alignas(16) u16 Psh[4][16 * 72];   // per-wave P: [q=16][key=64 pad 72]

    const u16* Kg = Kb + ((size_t)g) * 2048 * 64;
    const u16* Vg = Vt + ((size_t)g) * 64 * 2048;

    // Q B-frag: B[n=q][k=d], lane n=r16, k=q4*8+j (+32 for kk=1)
    bf16x8 qb[2];
    {
        const u16* qp = Qb + ((size_t)(g * 2048 + qt * 64 + w * 16 + r16)) * 64 + q4 * 8;
        qb[0] = *(const bf16x8*)qp;
        qb[1] = *(const bf16x8*)(qp + 32);
    }

    f32x4 o[4];
    const f32x4 zero = {0.f, 0.f, 0.f, 0.f};
    #pragma unroll
    for (int c = 0; c < 4; ++c) o[c] = zero;
    float m2 = -INFINITY, lsum = 0.f;

    // preload K-frags for tile 0: A[m=key][k=d], lane m=r16
    bf16x8 ka[4][2];
    #pragma unroll
    for (int kc = 0; kc < 4; ++kc) {
        const u16* kp = Kg + ((size_t)(kc * 16 + r16)) * 64 + q4 * 8;
        ka[kc][0] = *(const bf16x8*)kp;
        ka[kc][1] = *(const bf16x8*)(kp + 32);
    }

    u16* pw = Psh[w] + r16 * 72;

    for (int it = 0; it < 32; ++it) {
        // V^T A-frags for current tile: A[m=d][k=key], lane m=r16
        bf16x8 va[4][2];
        #pragma unroll
        for (int c = 0; c < 4; ++c) {
            const u16* vp = Vg + ((size_t)(c * 16 + r16)) * 2048 + it * 64 + q4 * 8;
            va[c][0] = *(const bf16x8*)vp;
            va[c][1] = *(const bf16x8*)(vp + 32);
        }

        // S^T = K.Q^T : lane holds q-col = r16, keys kc*16 + q4*4 + r
        f32x4 s[4];
        #pragma unroll
        for (int kc = 0; kc < 4; ++kc) {
            s[kc] = zero;
            s[kc] = __builtin_amdgcn_mfma_f32_16x16x32_bf16(ka[kc][0], qb[0], s[kc], 0, 0, 0);
            s[kc] = __builtin_amdgcn_mfma_f32_16x16x32_bf16(ka[kc][1], qb[1], s[kc], 0, 0, 0);
        }

        // prefetch next K tile while doing softmax
        bf16x8 kn[4][2];
        if (it < 31) {
            const u16* kb = Kg + ((size_t)((it + 1) * 64 + r16)) * 64 + q4 * 8;
            #pragma unroll
            for (int kc = 0; kc < 4; ++kc) {
                kn[kc][0] = *(const bf16x8*)(kb + (size_t)kc * 16 * 64);
                kn[kc][1] = *(const bf16x8*)(kb + (size_t)kc * 16 * 64 + 32);
            }
        }

        // online softmax — per-lane scalar state (q = r16)
        float mx = s[0][0];
        #pragma unroll
        for (int kc = 0; kc < 4; ++kc)
            #pragma unroll
            for (int r = 0; r < 4; ++r) mx = fmaxf(mx, s[kc][r]);
        mx = fmaxf(mx, __shfl_xor(mx, 16));
        mx = fmaxf(mx, __shfl_xor(mx, 32));
        float mn = fmaxf(m2, mx);
        float alpha = exp2f(m2 - mn);
        float p[4][4];
        float psum = 0.f;
        #pragma unroll
        for (int kc = 0; kc < 4; ++kc)
            #pragma unroll
            for (int r = 0; r < 4; ++r) {
                p[kc][r] = exp2f(s[kc][r] - mn);
                psum += p[kc][r];
            }
        lsum = lsum * alpha + psum;
        m2 = mn;
        #pragma unroll
        for (int c = 0; c < 4; ++c)
            #pragma unroll
            for (int r = 0; r < 4; ++r) o[c][r] *= alpha;

        // P^T (C-layout) -> LDS row q=r16: cols kc*16 + q4*4 + r  (b64 stores)
        #pragma unroll
        for (int kc = 0; kc < 4; ++kc) {
            uint2 dd = { pack2bf(p[kc][0], p[kc][1]), pack2bf(p[kc][2], p[kc][3]) };
            *(uint2*)(pw + kc * 16 + q4 * 4) = dd;
        }
        // B-frag read: B[n=q=r16][k=key=kk*32+q4*8+j]
        bf16x8 pb0 = *(const bf16x8*)(pw + q4 * 8);
        bf16x8 pb1 = *(const bf16x8*)(pw + 32 + q4 * 8);

        // O^T += V^T . P^T  : lane holds q-col r16, d rows c*16 + q4*4 + r
        #pragma unroll
        for (int c = 0; c < 4; ++c) {
            o[c] = __builtin_amdgcn_mfma_f32_16x16x32_bf16(va[c][0], pb0, o[c], 0, 0, 0);
            o[c] = __builtin_amdgcn_mfma_f32_16x16x32_bf16(va[c][1], pb1, o[c], 0, 0, 0);
        }

        #pragma unroll
        for (int kc = 0; kc < 4; ++kc) {
            ka[kc][0] = kn[kc][0];
            ka[kc][1] = kn[kc][1];
        }
    }

    // epilogue: reduce lsum over the 4 q4-lane groups, normalize, store
    float ls = lsum;
    ls += __shfl_xor(ls, 16);
    ls += __shfl_xor(ls, 32);
    float inv = 1.0f / ls;
    const int qq = qt * 64 + w * 16 + r16;
    u16* orow = Att + ((size_t)(g * 2048 + qq)) * 64;
    #pragma unroll
    for (int c = 0; c < 4; ++c) {
        u16x4 bb = { f2bf(o[c][0] * inv), f2bf(o[c][1] * inv),
                     f2bf(o[c][2] * inv), f2bf(o[c][3] * inv) };
        *(u16x4*)(orow + c * 16 + q4 * 4) = bb;
    }
}

// ---------------------------------------------------------------------------
// Kernel 3: out = Att @ Wfc^T + bfc.  M=4096, N=512, K=512.
// BM=128, BN=64, BK=64; grid (32, 8) = 256 blocks.  fp32 output.
// ---------------------------------------------------------------------------
__global__ __launch_bounds__(256) void fc_kernel(
    const u16* __restrict__ Att, const float* __restrict__ Wfc,
    const float* __restrict__ bfc, float* __restrict__ out)
{
    __shared__ alignas(16) u16 Ash[128 * 88];
    __shared__ alignas(16) u16 Wsh[64 * 88];

    const int t = threadIdx.x, w = t >> 6, l = t & 63;
    const int r16 = l & 15, q4 = l >> 4;
    const int m0 = blockIdx.x * 128, n0 = blockIdx.y * 64;

    f32x4 acc[2][4];
    const f32x4 zero = {0.f, 0.f, 0.f, 0.f};
    #pragma unroll
    for (int mc = 0; mc < 2; ++mc)
        #pragma unroll
        for (int nc = 0; nc < 4; ++nc) acc[mc][nc] = zero;

    for (int k0 = 0; k0 < 512; k0 += 64) {
        __syncthreads();
        {   // stage A (bf16 already): 128 x 64
            int c8 = t & 7;
            #pragma unroll
            for (int i = 0; i < 4; ++i) {
                int row = (t >> 3) + i * 32;
                *(u32x4*)(Ash + row * 88 + c8 * 8) =
                    *(const u32x4*)(Att + (size_t)(m0 + row) * 512 + k0 + c8 * 8);
            }
            // stage W (fp32 -> bf16): rows n0..n0+63, cols k0..k0+63
            int row = t >> 2;
            #pragma unroll
            for (int i = 0; i < 4; ++i) {
                int c4 = (t & 3) + i * 4;
                float4 val = *(const float4*)(Wfc + (size_t)(n0 + row) * 512 + k0 + c4 * 4);
                u16x4 bb = { f2bf(val.x), f2bf(val.y), f2bf(val.z), f2bf(val.w) };
                *(u16x4*)(Wsh + row * 88 + c4 * 4) = bb;
            }
        }
        __syncthreads();

        bf16x8 af[2][2], wf[4][2];
        #pragma unroll
        for (int mc = 0; mc < 2; ++mc)
            #pragma unroll
            for (int kk = 0; kk < 2; ++kk)
                af[mc][kk] = *(const bf16x8*)(Ash + (w * 32 + mc * 16 + r16) * 88 + kk * 32 + q4 * 8);
        #pragma unroll
        for (int nc = 0; nc < 4; ++nc)
            #pragma unroll
            for (int kk = 0; kk < 2; ++kk)
                wf[nc][kk] = *(const bf16x8*)(Wsh + (nc * 16 + r16) * 88 + kk * 32 + q4 * 8);

        #pragma unroll
        for (int mc = 0; mc < 2; ++mc)
            #pragma unroll
            for (int nc = 0; nc < 4; ++nc) {
                acc[mc][nc] = __builtin_amdgcn_mfma_f32_16x16x32_bf16(af[mc][0], wf[nc][0], acc[mc][nc], 0, 0, 0);
                acc[mc][nc] = __builtin_amdgcn_mfma_f32_16x16x32_bf16(af[mc][1], wf[nc][1], acc[mc][nc], 0, 0, 0);
            }
    }

    #pragma unroll
    for (int mc = 0; mc < 2; ++mc)
        #pragma unroll
        for (int nc = 0; nc < 4; ++nc)
            #pragma unroll
            for (int r = 0; r < 4; ++r) {
                int row = m0 + w * 32 + mc * 16 + q4 * 4 + r;
                int col = n0 + nc * 16 + r16;
                out[(size_t)row * 512 + col] = acc[mc][nc][r] + bfc[col];
            }
}

extern "C" void kernel_launch(void* const* d_in, const int* in_sizes, int n_in,
                              void* d_out, int out_size, void* d_ws, size_t ws_size,
                              hipStream_t stream) {
    (void)in_sizes; (void)n_in; (void)out_size; (void)ws_size;
    const float* q   = (const float*)d_in[0];
    const float* k   = (const float*)d_in[1];
    const float* v   = (const float*)d_in[2];
    const float* Wq  = (const float*)d_in[3];
    const float* Wk  = (const float*)d_in[4];
    const float* Wv  = (const float*)d_in[5];
    const float* Wfc = (const float*)d_in[6];
    const float* bfc = (const float*)d_in[7];
    float* out = (float*)d_out;

    u16* Qb = (u16*)d_ws;                 // 32768*64 bf16 (pre-scaled by sc*log2e)
    u16* Kb = Qb + 2097152;
    u16* Vt = Kb + 2097152;               // [16][64][2048]
    u16* At = Vt + 2097152;               // 32768*64 bf16

    proj_kernel<<<dim3(256, 1, 3), 256, 0, stream>>>(q, k, v, Wq, Wk, Wv, Qb, Kb, Vt);
    flash_kernel<<<dim3(32, 16), 256, 0, stream>>>(Qb, Kb, Vt, At);
    fc_kernel<<<dim3(32, 8), 256, 0, stream>>>(At, Wfc, bfc, out);
}